// Round 1
// baseline (212.961 us; speedup 1.0000x reference)
//
#include <hip/hip_runtime.h>
#include <hip/hip_bf16.h>

#define NN   1024
#define HD   64
#define MSGD 64
#define HIDD 128

typedef __attribute__((ext_vector_type(4))) float f4;
typedef __attribute__((ext_vector_type(2))) float f2;
typedef __attribute__((ext_vector_type(8))) __bf16 bf16x8;
typedef __attribute__((ext_vector_type(4))) float f32x4;
typedef __attribute__((ext_vector_type(4))) unsigned int u32x4;
typedef unsigned short ushort_t;

__device__ __forceinline__ float silu_f(float v) {
    float e = __expf(-v);
    return v * __builtin_amdgcn_rcpf(1.0f + e);
}

__device__ __forceinline__ ushort_t to_bf16_bits(float v) {
    return __builtin_bit_cast(ushort_t, (__bf16)v);
}

// ---------------------------------------------------------------------------
// Kernel A: Ah = h@ew1[0:64] + eb1, Bh = h@ew1[64:128]; pack ew2/cw1 into
// MFMA B-fragment order (bf16).  Fragment layout for mfma_f32_16x16x32_bf16:
// B[k][n]: lane l holds n = l&15, k = (l>>4)*8 + e, e in [0,8).
// ---------------------------------------------------------------------------
__global__ void egnn_pre(const float* __restrict__ h, const float* __restrict__ ew1,
                         const float* __restrict__ eb1, const float* __restrict__ ew2,
                         const float* __restrict__ cw1,
                         float* __restrict__ Ah, float* __restrict__ Bh,
                         ushort_t* __restrict__ ew2f, ushort_t* __restrict__ cw1f)
{
    const int b = blockIdx.x, tid = threadIdx.x;
    if (b < 128) {
        const int n = b * 8 + (tid >> 5);
        const int c = (tid & 31) * 4;
        f4 a = *(const f4*)&eb1[c];
        f4 bb = (f4){0.f, 0.f, 0.f, 0.f};
        const float* hrow = h + n * HD;
        #pragma unroll 4
        for (int d = 0; d < HD; ++d) {
            const float hv = hrow[d];
            const f4 w1 = *(const f4*)&ew1[d * HIDD + c];
            const f4 w2 = *(const f4*)&ew1[(HD + d) * HIDD + c];
            a += hv * w1;
            bb += hv * w2;
        }
        *(f4*)&Ah[n * HIDD + c] = a;
        *(f4*)&Bh[n * HIDD + c] = bb;
    } else if (b == 128) {
        // ew2: [128][64] -> frags [ks(4)][nt(4)][lane(64)][e(8)]
        #pragma unroll
        for (int uu = 0; uu < 4; ++uu) {
            const int fl = uu * 256 + tid;
            const int f = fl >> 6, lane = fl & 63;
            const int ks = f >> 2, nt = f & 3, lq = lane >> 4, lr = lane & 15;
            float vals[8];
            #pragma unroll
            for (int e = 0; e < 8; ++e)
                vals[e] = ew2[(ks * 32 + lq * 8 + e) * MSGD + nt * 16 + lr];
            u32x4 pk;
            #pragma unroll
            for (int p = 0; p < 4; ++p)
                pk[p] = (unsigned)to_bf16_bits(vals[2 * p]) |
                        ((unsigned)to_bf16_bits(vals[2 * p + 1]) << 16);
            *(u32x4*)&ew2f[fl * 8] = pk;
        }
    } else {
        // cw1: [64][128] -> frags [ks2(2)][nt(8)][lane(64)][e(8)]
        #pragma unroll
        for (int uu = 0; uu < 4; ++uu) {
            const int fl = uu * 256 + tid;
            const int f = fl >> 6, lane = fl & 63;
            const int ks = f >> 3, nt = f & 7, lq = lane >> 4, lr = lane & 15;
            float vals[8];
            #pragma unroll
            for (int e = 0; e < 8; ++e)
                vals[e] = cw1[(ks * 32 + lq * 8 + e) * HIDD + nt * 16 + lr];
            u32x4 pk;
            #pragma unroll
            for (int p = 0; p < 4; ++p)
                pk[p] = (unsigned)to_bf16_bits(vals[2 * p]) |
                        ((unsigned)to_bf16_bits(vals[2 * p + 1]) << 16);
            *(u32x4*)&cw1f[fl * 8] = pk;
        }
    }
}

// ---------------------------------------------------------------------------
// Kernel B: the fused per-edge pipeline.
// WG = 4 waves, wave w owns node i = blockIdx.x*4 + w.
// blockIdx.y in {0,1} selects a 512-wide j-half; j chunks of 32.
// Per chunk per wave: build s (silu of factored hidden1) in A-frag layout,
// MFMA s@ew2 -> m (C layout: col=lane&15, row=(lane>>4)*4+reg), add eb2,
// zero self-row, accumulate m_i, stash m as bf16 in per-wave LDS,
// MFMA m@cw1 -> t, silu, dot cw2 -> phi, accumulate dx*phi.
// ---------------------------------------------------------------------------
__global__ __launch_bounds__(256, 2) void egnn_edge(
    const float* __restrict__ x, const float* __restrict__ wr_row,
    const float* __restrict__ Ah, const float* __restrict__ Bh,
    const ushort_t* __restrict__ ew2f, const ushort_t* __restrict__ cw1f,
    const float* __restrict__ eb2, const float* __restrict__ cb1,
    const float* __restrict__ cw2, const float* __restrict__ cb2,
    float* __restrict__ m_part, float* __restrict__ xu_part)
{
    __shared__ ushort_t ew2_lds[16][512];   // 16 KB
    __shared__ ushort_t cw1_lds[16][512];   // 16 KB
    __shared__ float    bh_lds[32][132];    // 16.9 KB (pad +4 -> 2-way max)
    __shared__ ushort_t m_lds[4][32][72];   // 18 KB per-wave m (bf16), pad +8
    __shared__ float    ah_lds[4][132];     // 2.1 KB
    __shared__ float    xj_lds[32][4];
    __shared__ float    r2_lds[4][32];

    const int tid = threadIdx.x;
    const int w = tid >> 6, lane = tid & 63, lq = lane >> 4, lr = lane & 15;
    const int i0 = blockIdx.x * 4;
    const int jh = blockIdx.y;
    const int i = i0 + w;

    // prologue: weight frags + Ah rows into LDS
    {
        const u32x4* s1 = (const u32x4*)ew2f;
        const u32x4* s2 = (const u32x4*)cw1f;
        u32x4* d1 = (u32x4*)&ew2_lds[0][0];
        u32x4* d2 = (u32x4*)&cw1_lds[0][0];
        #pragma unroll
        for (int uu = 0; uu < 4; ++uu) {
            const int idx = uu * 256 + tid;
            d1[idx] = s1[idx];
            d2[idx] = s2[idx];
        }
        const int r = tid >> 6, c = (tid & 63) * 2;
        const f2 v = *(const f2*)&Ah[(i0 + r) * HIDD + c];
        ah_lds[r][c] = v[0];
        ah_lds[r][c + 1] = v[1];
    }

    // per-lane preloads (L1-broadcast, one time)
    float cb1v[8], cw2v[8], eb2v[4];
    #pragma unroll
    for (int nt = 0; nt < 8; ++nt) { cb1v[nt] = cb1[nt * 16 + lr]; cw2v[nt] = cw2[nt * 16 + lr]; }
    #pragma unroll
    for (int nt = 0; nt < 4; ++nt) eb2v[nt] = eb2[nt * 16 + lr];
    const float cb2s = cb2[0];
    const float xi0 = x[i * 3 + 0], xi1 = x[i * 3 + 1], xi2 = x[i * 3 + 2];

    float m_acc[4] = {0.f, 0.f, 0.f, 0.f};
    float xq0 = 0.f, xq1 = 0.f, xq2 = 0.f;

    for (int jc = 0; jc < 16; ++jc) {
        const int j0 = jh * 512 + jc * 32;
        __syncthreads();                       // protect prior chunk reads
        // stage Bh chunk (32 rows x 128 f32) and xj
        #pragma unroll
        for (int uu = 0; uu < 4; ++uu) {
            const int idx = uu * 256 + tid;
            const int row = idx >> 5, c4 = (idx & 31) * 4;
            const f4 v = *(const f4*)&Bh[(j0 + row) * HIDD + c4];
            *(f4*)&bh_lds[row][c4] = v;
        }
        if (tid < 96) {
            const int r = tid / 3, c = tid - 3 * r;
            xj_lds[r][c] = x[(j0 + r) * 3 + c];
        }
        __syncthreads();
        // r2 per wave (per-wave buffer, same-wave dependency only)
        if (lane < 32) {
            const float d0 = xi0 - xj_lds[lane][0];
            const float d1 = xi1 - xj_lds[lane][1];
            const float d2 = xi2 - xj_lds[lane][2];
            r2_lds[w][lane] = d0 * d0 + d1 * d1 + d2 * d2;
        }

        // ---- GEMM1: m = silu(h1) @ ew2 ----
        f32x4 accm[2][4];
        #pragma unroll
        for (int mt = 0; mt < 2; ++mt)
            #pragma unroll
            for (int nt = 0; nt < 4; ++nt)
                accm[mt][nt] = (f32x4){0.f, 0.f, 0.f, 0.f};

        #pragma unroll
        for (int ks = 0; ks < 4; ++ks) {
            const int kb = ks * 32 + lq * 8;
            const f4 wr0 = *(const f4*)&wr_row[kb];
            const f4 wr1 = *(const f4*)&wr_row[kb + 4];
            const f4 a0 = *(const f4*)&ah_lds[w][kb];
            const f4 a1 = *(const f4*)&ah_lds[w][kb + 4];
            bf16x8 aS[2];
            #pragma unroll
            for (int mt = 0; mt < 2; ++mt) {
                const int jl = mt * 16 + lr;
                const float r2v = r2_lds[w][jl];
                const f4 b0 = *(const f4*)&bh_lds[jl][kb];
                const f4 b1 = *(const f4*)&bh_lds[jl][kb + 4];
                #pragma unroll
                for (int e = 0; e < 4; ++e) {
                    const float s0 = silu_f(a0[e] + b0[e] + r2v * wr0[e]);
                    const float s1 = silu_f(a1[e] + b1[e] + r2v * wr1[e]);
                    aS[mt][e] = (__bf16)s0;
                    aS[mt][e + 4] = (__bf16)s1;
                }
            }
            #pragma unroll
            for (int nt = 0; nt < 4; ++nt) {
                const bf16x8 bfr = *(const bf16x8*)&ew2_lds[ks * 4 + nt][lane * 8];
                accm[0][nt] = __builtin_amdgcn_mfma_f32_16x16x32_bf16(aS[0], bfr, accm[0][nt], 0, 0, 0);
                accm[1][nt] = __builtin_amdgcn_mfma_f32_16x16x32_bf16(aS[1], bfr, accm[1][nt], 0, 0, 0);
            }
        }
        // eb2 bias
        #pragma unroll
        for (int mt = 0; mt < 2; ++mt)
            #pragma unroll
            for (int nt = 0; nt < 4; ++nt)
                #pragma unroll
                for (int r = 0; r < 4; ++r)
                    accm[mt][nt][r] += eb2v[nt];
        // zero self-edge row (only one chunk per WG can contain it)
        if (i0 >= j0 && i0 < j0 + 32) {
            #pragma unroll
            for (int mt = 0; mt < 2; ++mt)
                #pragma unroll
                for (int r = 0; r < 4; ++r) {
                    const bool self = (j0 + mt * 16 + lq * 4 + r) == i;
                    #pragma unroll
                    for (int nt = 0; nt < 4; ++nt)
                        accm[mt][nt][r] = self ? 0.f : accm[mt][nt][r];
                }
        }
        // m_i accumulate + stash m as bf16 (per-wave LDS region)
        #pragma unroll
        for (int mt = 0; mt < 2; ++mt)
            #pragma unroll
            for (int nt = 0; nt < 4; ++nt)
                #pragma unroll
                for (int r = 0; r < 4; ++r) {
                    const float mv = accm[mt][nt][r];
                    m_acc[nt] += mv;
                    m_lds[w][mt * 16 + lq * 4 + r][nt * 16 + lr] = to_bf16_bits(mv);
                }

        // ---- GEMM2: t = m @ cw1, phi = silu(t)@cw2 + cb2 ----
        float phip[2][4];
        #pragma unroll
        for (int mt = 0; mt < 2; ++mt)
            #pragma unroll
            for (int r = 0; r < 4; ++r)
                phip[mt][r] = 0.f;

        #pragma unroll
        for (int nh = 0; nh < 2; ++nh) {
            f32x4 acct[2][4];
            #pragma unroll
            for (int mt = 0; mt < 2; ++mt)
                #pragma unroll
                for (int nt = 0; nt < 4; ++nt)
                    acct[mt][nt] = (f32x4){0.f, 0.f, 0.f, 0.f};
            #pragma unroll
            for (int ks = 0; ks < 2; ++ks) {
                bf16x8 aM[2];
                #pragma unroll
                for (int mt = 0; mt < 2; ++mt)
                    aM[mt] = *(const bf16x8*)&m_lds[w][mt * 16 + lr][ks * 32 + lq * 8];
                #pragma unroll
                for (int nt = 0; nt < 4; ++nt) {
                    const bf16x8 bfr = *(const bf16x8*)&cw1_lds[ks * 8 + nh * 4 + nt][lane * 8];
                    acct[0][nt] = __builtin_amdgcn_mfma_f32_16x16x32_bf16(aM[0], bfr, acct[0][nt], 0, 0, 0);
                    acct[1][nt] = __builtin_amdgcn_mfma_f32_16x16x32_bf16(aM[1], bfr, acct[1][nt], 0, 0, 0);
                }
            }
            #pragma unroll
            for (int mt = 0; mt < 2; ++mt)
                #pragma unroll
                for (int nt = 0; nt < 4; ++nt)
                    #pragma unroll
                    for (int r = 0; r < 4; ++r) {
                        const float tt = acct[mt][nt][r] + cb1v[nh * 4 + nt];
                        phip[mt][r] += silu_f(tt) * cw2v[nh * 4 + nt];
                    }
        }
        // reduce phi over the 16 lr lanes
        #pragma unroll
        for (int d = 1; d < 16; d <<= 1)
            #pragma unroll
            for (int mt = 0; mt < 2; ++mt)
                #pragma unroll
                for (int r = 0; r < 4; ++r)
                    phip[mt][r] += __shfl_xor(phip[mt][r], d);
        // x-update accumulation (lr==0 lanes carry; dx=0 kills self edge)
        #pragma unroll
        for (int mt = 0; mt < 2; ++mt)
            #pragma unroll
            for (int r = 0; r < 4; ++r) {
                const int jl = mt * 16 + lq * 4 + r;
                const float phi = (lr == 0) ? (phip[mt][r] + cb2s) : 0.f;
                xq0 += (xi0 - xj_lds[jl][0]) * phi;
                xq1 += (xi1 - xj_lds[jl][1]) * phi;
                xq2 += (xi2 - xj_lds[jl][2]) * phi;
            }
    }

    // epilogue: finish m_i (sum lq groups) and xq (sum all lanes), write partials
    #pragma unroll
    for (int nt = 0; nt < 4; ++nt) {
        m_acc[nt] += __shfl_xor(m_acc[nt], 16);
        m_acc[nt] += __shfl_xor(m_acc[nt], 32);
    }
    if (lane < 16) {
        #pragma unroll
        for (int nt = 0; nt < 4; ++nt)
            m_part[(jh * NN + i) * MSGD + nt * 16 + lane] = m_acc[nt];
    }
    #pragma unroll
    for (int d = 1; d < 64; d <<= 1) {
        xq0 += __shfl_xor(xq0, d);
        xq1 += __shfl_xor(xq1, d);
        xq2 += __shfl_xor(xq2, d);
    }
    if (lane == 0) {
        float* dst = &xu_part[(jh * NN + i) * 3];
        dst[0] = xq0; dst[1] = xq1; dst[2] = xq2;
    }
}

// ---------------------------------------------------------------------------
// Kernel C: reduce partials, node MLP (fp32), write outputs.
// 128 blocks x 8 rows.
// ---------------------------------------------------------------------------
__global__ void egnn_node(const float* __restrict__ x, const float* __restrict__ h,
                          const float* __restrict__ nw1, const float* __restrict__ nb1,
                          const float* __restrict__ nw2, const float* __restrict__ nb2,
                          const float* __restrict__ m_part, const float* __restrict__ xu_part,
                          float* __restrict__ out)
{
    __shared__ float nin[8][132];
    __shared__ float zl[8][132];
    const int tid = threadIdx.x;
    const int r0 = blockIdx.x * 8;
    #pragma unroll
    for (int uu = 0; uu < 4; ++uu) {
        const int idx = uu * 256 + tid;
        const int row = idx >> 7, c = idx & 127;
        float v;
        if (c < 64) v = h[(r0 + row) * HD + c];
        else v = m_part[(r0 + row) * MSGD + (c - 64)] + m_part[(NN + r0 + row) * MSGD + (c - 64)];
        nin[row][c] = v;
    }
    __syncthreads();
    const int row = tid >> 5, cg = tid & 31;
    {
        const int c0 = cg * 4;
        f4 acc = *(const f4*)&nb1[c0];
        for (int k = 0; k < 128; ++k) {
            const float v = nin[row][k];
            const f4 wv = *(const f4*)&nw1[k * HIDD + c0];
            acc += v * wv;
        }
        #pragma unroll
        for (int e = 0; e < 4; ++e) zl[row][c0 + e] = silu_f(acc[e]);
    }
    __syncthreads();
    {
        const int c0 = cg * 2;
        f2 acc = *(const f2*)&nb2[c0];
        for (int k = 0; k < 128; ++k) {
            const float v = zl[row][k];
            const f2 wv = *(const f2*)&nw2[k * HD + c0];
            acc += v * wv;
        }
        const int n = r0 + row;
        const f2 hv = *(const f2*)&h[n * HD + c0];
        *(f2*)&out[3072 + n * HD + c0] = hv + acc;
    }
    if (tid < 24) {
        const int r = tid / 3, c = tid - 3 * r;
        const int n = r0 + r;
        const float xu = xu_part[n * 3 + c] + xu_part[(NN + n) * 3 + c];
        out[n * 3 + c] = x[n * 3 + c] + xu * (1.0f / 1023.0f);
    }
}

// ---------------------------------------------------------------------------
extern "C" void kernel_launch(void* const* d_in, const int* in_sizes, int n_in,
                              void* d_out, int out_size, void* d_ws, size_t ws_size,
                              hipStream_t stream)
{
    const float* x   = (const float*)d_in[0];
    const float* h   = (const float*)d_in[1];
    const float* ew1 = (const float*)d_in[2];
    const float* eb1 = (const float*)d_in[3];
    const float* ew2 = (const float*)d_in[4];
    const float* eb2 = (const float*)d_in[5];
    const float* nw1 = (const float*)d_in[6];
    const float* nb1 = (const float*)d_in[7];
    const float* nw2 = (const float*)d_in[8];
    const float* nb2 = (const float*)d_in[9];
    const float* cw1 = (const float*)d_in[10];
    const float* cb1 = (const float*)d_in[11];
    const float* cw2 = (const float*)d_in[12];
    const float* cb2 = (const float*)d_in[13];
    float* out = (float*)d_out;

    char* ws = (char*)d_ws;
    float*    Ah      = (float*)(ws);                          // 512 KB
    float*    Bh      = (float*)(ws + 524288);                 // 512 KB
    ushort_t* ew2f    = (ushort_t*)(ws + 1048576);             // 16 KB
    ushort_t* cw1f    = (ushort_t*)(ws + 1048576 + 16384);     // 16 KB
    float*    m_part  = (float*)(ws + 1048576 + 32768);        // 512 KB
    float*    xu_part = (float*)(ws + 1048576 + 32768 + 524288); // 24 KB

    egnn_pre<<<dim3(130), dim3(256), 0, stream>>>(h, ew1, eb1, ew2, cw1, Ah, Bh, ew2f, cw1f);
    egnn_edge<<<dim3(256, 2), dim3(256), 0, stream>>>(
        x, ew1 + 128 * HIDD, Ah, Bh, ew2f, cw1f, eb2, cb1, cw2, cb2, m_part, xu_part);
    egnn_node<<<dim3(128), dim3(256), 0, stream>>>(x, h, nw1, nb1, nw2, nb2, m_part, xu_part, out);
}